// Round 1
// baseline (173.733 us; speedup 1.0000x reference)
//
#include <hip/hip_runtime.h>
#include <hip/hip_bf16.h>

#define B_ 1024
#define P_ 8
#define D_ 2048
#define FD_ (P_ * D_)   // 16384
#define NID 64
#define MARGIN_ 0.3f
#define EPS_ 1e-12f

typedef unsigned short u16;
typedef float float4_t __attribute__((ext_vector_type(4)));
typedef long long2_t __attribute__((ext_vector_type(2)));

#define AS1 __attribute__((address_space(1)))
#define AS3 __attribute__((address_space(3)))

__device__ __forceinline__ float bf2f(u16 v) {
    unsigned x = (unsigned)v << 16;
    float f;
    __builtin_memcpy(&f, &x, 4);
    return f;
}

// ---------------- workspace layout (bytes) ----------------
static const size_t OFF_COUNTS = 0;         // 64 fp32
static const size_t OFF_OFFS   = 256;       // 64 int
static const size_t OFF_PERM   = 512;       // 1024 int -> ends 4608
static const size_t OFF_NEG    = 4608;
static const size_t OFF_POS    = 8176;      // adjacent to S so one memset covers both
static const size_t OFF_S      = 8192;      // 1024*8 fp32 = 32 KB -> 40960
static const size_t OFF_SQ     = 40960;     // 1024*8 fp32 = 32 KB -> 73728
static const size_t OFF_DAP    = 73728;     // 1024 fp32 -> 77824
static const size_t OFF_FB     = 131072;    // 1024*16384 fp8 = 16 MB
static const size_t OFF_PD     = OFF_FB + (size_t)B_ * FD_;  // 8 planes * 1024*1024 bf16 = 16 MB
// total ~33.7 MB

// ---------------- kernel 1: histogram counts + prefix + perm + negcnt ----------------
__global__ void k_counts(const int* __restrict__ labels, float* countsf, int* offs,
                         int* perm, float* negcnt) {
    __shared__ int h[NID], o[NID], cur[NID];
    int tid = threadIdx.x;
    if (tid < NID) h[tid] = 0;
    __syncthreads();
    for (int i = tid; i < B_; i += 256) atomicAdd(&h[labels[i]], 1);
    __syncthreads();
    if (tid == 0) {
        int acc = 0;
        long long ss = 0;
        for (int c = 0; c < NID; c++) {
            o[c] = acc;
            acc += h[c];
            ss += (long long)h[c] * h[c];
        }
        *negcnt = (float)((long long)B_ * B_ - ss);
    }
    __syncthreads();
    if (tid < NID) {
        countsf[tid] = (float)h[tid];
        offs[tid] = o[tid];
        cur[tid] = o[tid];
    }
    __syncthreads();
    for (int i = tid; i < B_; i += 256) {
        int pos = atomicAdd(&cur[labels[i]], 1);
        perm[pos] = i;
    }
}

// ---------------- kernel 2: fp8 cast + sq (wave-per-plane-pair) ----------------
// fb is written in "k-grouped" layout: within each 64-B window of a row, byte
// (ks*32 + lhi*8 + b) is stored at (lhi*16 + ks*8 + b). This makes each lane's two
// K-step MFMA operands contiguous so k_pairs can use ds_read_b128.
__global__ void k_rowstats(const float* __restrict__ feats, unsigned char* __restrict__ fb,
                           float* __restrict__ sq) {
    int i = blockIdx.x;
    int tid = threadIdx.x;
    int w = tid >> 6, lane = tid & 63;
    const float* frow = feats + (size_t)i * FD_;
    unsigned char* brow = fb + (size_t)i * FD_;
    // this thread's 4 fp8 bytes live at window-local offset (lane&15)*4:
    //   ks = (lane>>3)&1, lhi = (lane>>1)&3, b = (lane&1)*4
    const int wsel = (lane >> 4) * 64;  // which 64-B window of the 256-B chunk
    const int no = ((lane >> 1) & 3) * 16 + ((lane >> 3) & 1) * 8 + (lane & 1) * 4;
#pragma unroll
    for (int pp = 0; pp < 2; pp++) {
        int p = w * 2 + pp;
        int off = p * D_;
        float s2 = 0.f;
#pragma unroll
        for (int ch = 0; ch < 8; ch++) {
            int d = off + ch * 256 + lane * 4;
            float4 f = *(const float4*)(frow + d);
            int pk = __builtin_amdgcn_cvt_pk_fp8_f32(f.x, f.y, 0, false);
            pk = __builtin_amdgcn_cvt_pk_fp8_f32(f.z, f.w, pk, true);
            *(unsigned int*)(brow + off + ch * 256 + wsel + no) = (unsigned int)pk;
            s2 += f.x * f.x + f.y * f.y + f.z * f.z + f.w * f.w;
        }
        for (int o = 32; o; o >>= 1) s2 += __shfl_down(s2, o, 64);
        if (lane == 0) sq[i * P_ + p] = s2;
    }
}

// ---------------- kernel 3: fp8 MFMA pair kernel (double-buffered prefetch) ----------------
// grid (8,8,8): 128x128 (i,j) tile, z = plane p. block 512 = 4 spatial x 2 K-half waves.
// K window per step = 64 B (fp8), 16 steps per half, double-buffered (2 x 32 KB LDS).
// STAGE(next) is issued BEFORE COMPUTE(cur); one __syncthreads per K-step drains the
// prefetch vmcnt after a full compute phase (minimum 2-phase pipeline).
// LDS layout per buffer: [A h0 8K][A h1 8K][B h0 8K][B h1 8K]; row stride 64 B with
// XOR chunk swizzle: phys 16-B chunk = logical ^ ((row>>1)&3), achieved by
// pre-swizzling the per-lane GLOBAL source (linear global_load_lds dest).
// Frags: one ds_read_b128 per row-group = both K-steps (fb is k-grouped, see k_rowstats).
__global__ __launch_bounds__(512, 4) void k_pairs(const unsigned char* __restrict__ fb,
                                                  const float* __restrict__ sq,
                                                  const int* __restrict__ labels,
                                                  float* __restrict__ S,
                                                  u16* __restrict__ pd) {
    const int i0 = blockIdx.y * 128, j0 = blockIdx.x * 128;
    const int p = blockIdx.z;
    __shared__ __align__(16) unsigned char smem[65536];
    __shared__ float sqAs[128], sqBs[128];
    __shared__ int labA[128], labB[128];
    const int tid = threadIdx.x;
    const int lane = tid & 63, wid = tid >> 6;
    const int s = wid & 3, h = wid >> 2;
    if (tid < 128) {
        sqAs[tid] = sq[(i0 + tid) * 8 + p];
        labA[tid] = labels[i0 + tid];
    } else if (tid < 256) {
        int t = tid - 128;
        sqBs[t] = sq[(j0 + t) * 8 + p];
        labB[t] = labels[j0 + t];
    }

    const int wi = (s >> 1) * 64, wj = (s & 1) * 64;
    const int lhi = lane >> 4, llo = lane & 15;

    // ---- staging addresses: lane covers row r0+(lane>>2), phys chunk lane&3 ----
    // phys chunk q holds logical chunk q ^ s(row), s(row) = (row>>1)&3 = (lane>>3)&3
    const int srcsw = ((lane & 3) ^ ((lane >> 3) & 3)) << 4;
    const size_t colbase = (size_t)p * D_ + (size_t)h * 1024 + srcsw;
    const unsigned char* gA[2];
    const unsigned char* gB[2];
    unsigned char* lA[2];  // buffer-0 LDS dests (wave-uniform; HW adds lane*16)
    unsigned char* lB[2];
#pragma unroll
    for (int inst = 0; inst < 2; inst++) {
        const int r0 = s * 32 + inst * 16;
        gA[inst] = fb + (size_t)(i0 + r0 + (lane >> 2)) * FD_ + colbase;
        gB[inst] = fb + (size_t)(j0 + r0 + (lane >> 2)) * FD_ + colbase;
        lA[inst] = smem + h * 8192 + r0 * 64;
        lB[inst] = smem + 16384 + h * 8192 + r0 * 64;
    }

    // ---- fragment read addresses (buffer 0; buffer 1 = +32768) ----
    // lane reads phys chunk lhi ^ ((llo>>1)&3) of row (w + a*16 + llo):
    // 16 B = [ks0 8B | ks1 8B] thanks to the k-grouped fb layout
    const int csw = (lhi ^ ((llo >> 1) & 3)) << 4;
    const unsigned char* aAddr[4];
    const unsigned char* bAddr[4];
#pragma unroll
    for (int a = 0; a < 4; a++) {
        aAddr[a] = smem + h * 8192 + (wi + a * 16 + llo) * 64 + csw;
        bAddr[a] = smem + 16384 + h * 8192 + (wj + a * 16 + llo) * 64 + csw;
    }

    float4_t acc[4][4];
#pragma unroll
    for (int a = 0; a < 4; a++)
#pragma unroll
        for (int b = 0; b < 4; b++) acc[a][b] = (float4_t){0.f, 0.f, 0.f, 0.f};

#define STAGE(BUF, KOFF)                                                                  \
    {                                                                                     \
        __builtin_amdgcn_global_load_lds((const AS1 void*)(gA[0] + (KOFF)),               \
                                         (AS3 void*)(lA[0] + (BUF)*32768), 16, 0, 0);     \
        __builtin_amdgcn_global_load_lds((const AS1 void*)(gB[0] + (KOFF)),               \
                                         (AS3 void*)(lB[0] + (BUF)*32768), 16, 0, 0);     \
        __builtin_amdgcn_global_load_lds((const AS1 void*)(gA[1] + (KOFF)),               \
                                         (AS3 void*)(lA[1] + (BUF)*32768), 16, 0, 0);     \
        __builtin_amdgcn_global_load_lds((const AS1 void*)(gB[1] + (KOFF)),               \
                                         (AS3 void*)(lB[1] + (BUF)*32768), 16, 0, 0);     \
    }

#define COMPUTE(BUF)                                                                      \
    {                                                                                     \
        long2_t af[4], bq[4];                                                             \
        _Pragma("unroll") for (int a = 0; a < 4; a++) {                                   \
            af[a] = *(const long2_t*)(aAddr[a] + (BUF)*32768);                            \
            bq[a] = *(const long2_t*)(bAddr[a] + (BUF)*32768);                            \
        }                                                                                 \
        _Pragma("unroll") for (int a = 0; a < 4; a++)                                     \
            _Pragma("unroll") for (int b = 0; b < 4; b++)                                 \
                acc[a][b] = __builtin_amdgcn_mfma_f32_16x16x32_fp8_fp8(                   \
                    af[a].x, bq[b].x, acc[a][b], 0, 0, 0);                                \
        _Pragma("unroll") for (int a = 0; a < 4; a++)                                     \
            _Pragma("unroll") for (int b = 0; b < 4; b++)                                 \
                acc[a][b] = __builtin_amdgcn_mfma_f32_16x16x32_fp8_fp8(                   \
                    af[a].y, bq[b].y, acc[a][b], 0, 0, 0);                                \
    }

    STAGE(0, 0);
    __syncthreads();
#pragma unroll 1
    for (int kb2 = 0; kb2 < 7; kb2++) {
        STAGE(1, (kb2 * 2 + 1) * 64);
        COMPUTE(0);
        __syncthreads();
        STAGE(0, (kb2 * 2 + 2) * 64);
        COMPUTE(1);
        __syncthreads();
    }
    STAGE(1, 15 * 64);
    COMPUTE(0);
    __syncthreads();
    COMPUTE(1);

#undef STAGE
#undef COMPUTE

    // ---- epilogue: combine K-halves, sqrt -> pd, masked row sums -> S ----
    __syncthreads();  // all ds_reads of smem done before reuse
    float* ep = (float*)smem;
    if (h == 1) {
#pragma unroll
        for (int a = 0; a < 4; a++)
#pragma unroll
            for (int b = 0; b < 4; b++)
                *(float4_t*)&ep[(((s * 4 + a) * 4 + b) * 64 + lane) * 4] = acc[a][b];
    }
    __syncthreads();
    if (h == 0) {
        u16* outp = pd + (size_t)p * B_ * B_;
        float rs[4][4];
#pragma unroll
        for (int a = 0; a < 4; a++)
#pragma unroll
            for (int r = 0; r < 4; r++) rs[a][r] = 0.f;
#pragma unroll
        for (int a = 0; a < 4; a++) {
            int la0 = labA[wi + a * 16 + lhi * 4 + 0];
            int la1 = labA[wi + a * 16 + lhi * 4 + 1];
            int la2 = labA[wi + a * 16 + lhi * 4 + 2];
            int la3 = labA[wi + a * 16 + lhi * 4 + 3];
#pragma unroll
            for (int b = 0; b < 4; b++) {
                float4_t o = *(const float4_t*)&ep[(((s * 4 + a) * 4 + b) * 64 + lane) * 4];
                int lb = labB[wj + b * 16 + llo];
                int jl = wj + b * 16 + llo;
#pragma unroll
                for (int r = 0; r < 4; r++) {
                    int il = wi + a * 16 + lhi * 4 + r;
                    float t = acc[a][b][r] + o[r];
                    float d2 = sqAs[il] + sqBs[jl] - 2.0f * t;
                    outp[(size_t)(i0 + il) * B_ + (j0 + jl)] =
                        __bfloat16_as_ushort(__float2bfloat16(sqrtf(fmaxf(d2, EPS_))));
                    int la = (r == 0) ? la0 : (r == 1) ? la1 : (r == 2) ? la2 : la3;
                    if (lb == la) rs[a][r] += t;
                }
            }
        }
#pragma unroll
        for (int a = 0; a < 4; a++)
#pragma unroll
            for (int r = 0; r < 4; r++) {
                float v = rs[a][r];
                v += __shfl_xor(v, 1, 64);
                v += __shfl_xor(v, 2, 64);
                v += __shfl_xor(v, 4, 64);
                v += __shfl_xor(v, 8, 64);
                if (llo == 0)
                    atomicAdd(&S[(size_t)(i0 + wi + a * 16 + lhi * 4 + r) * 8 + p], v);
            }
    }
}

// ---------------- kernel 4: d_ap from Gram row sums ----------------
// grid 64 (one class), block 64
__global__ void k_dap(const float* __restrict__ S, const float* __restrict__ sq,
                      const float* __restrict__ countsf, const int* __restrict__ offs,
                      const int* __restrict__ perm, float* __restrict__ dap) {
    int c = blockIdx.x;
    int tid = threadIdx.x;
    int cnt = (int)countsf[c];
    int off = offs[c];
    __shared__ float T[8];
    if (tid < 8) {
        float t = 0.f;
        for (int m = 0; m < cnt; m++) t += S[(size_t)perm[off + m] * 8 + tid];
        T[tid] = t;
    }
    __syncthreads();
    float n = fmaxf((float)cnt, 1.f);
    float inv = 1.f / n, inv2 = inv * inv;
    for (int m = tid; m < cnt; m += 64) {
        int i = perm[off + m];
        float d = 0.f;
#pragma unroll
        for (int p = 0; p < 8; p++) {
            float d2 = sq[i * 8 + p] - 2.f * inv * S[(size_t)i * 8 + p] + inv2 * T[p];
            d += sqrtf(fmaxf(d2, EPS_));
        }
        dap[i] = d;
    }
}

// ---------------- kernel 5: masked margin reduction over 8 bf16 planes ----------------
// vectorized: each thread owns 4 consecutive j (ushort4 pd loads, 8 B/lane)
__global__ void k_lossred(const u16* __restrict__ pd, const float* __restrict__ dap,
                          const int* __restrict__ labels, float* possum) {
    int i = blockIdx.x;
    int tid = threadIdx.x;  // 256
    float di = dap[i];
    int li = labels[i];
    int j0 = tid * 4;
    float d0 = 0.f, d1 = 0.f, d2 = 0.f, d3 = 0.f;
#pragma unroll
    for (int p = 0; p < P_; p++) {
        ushort4 v = *(const ushort4*)&pd[(size_t)p * B_ * B_ + (size_t)i * B_ + j0];
        d0 += bf2f(v.x);
        d1 += bf2f(v.y);
        d2 += bf2f(v.z);
        d3 += bf2f(v.w);
    }
    int4 lj = *(const int4*)&labels[j0];
    float4 dj = *(const float4*)&dap[j0];
    float lsum = 0.f;
    if (lj.x != li) lsum += fmaxf(di + dj.x - d0 + MARGIN_, 0.f);
    if (lj.y != li) lsum += fmaxf(di + dj.y - d1 + MARGIN_, 0.f);
    if (lj.z != li) lsum += fmaxf(di + dj.z - d2 + MARGIN_, 0.f);
    if (lj.w != li) lsum += fmaxf(di + dj.w - d3 + MARGIN_, 0.f);
    for (int o = 32; o; o >>= 1) lsum += __shfl_down(lsum, o, 64);
    __shared__ float red[4];
    int wid = tid >> 6, lane = tid & 63;
    if (lane == 0) red[wid] = lsum;
    __syncthreads();
    if (tid == 0) atomicAdd(possum, red[0] + red[1] + red[2] + red[3]);
}

__global__ void k_finalize(const float* possum, const float* negcnt, float* out) {
    out[0] = possum[0] / negcnt[0];
}

// ---------------- launch ----------------
extern "C" void kernel_launch(void* const* d_in, const int* in_sizes, int n_in,
                              void* d_out, int out_size, void* d_ws, size_t ws_size,
                              hipStream_t stream) {
    const float* feats = (const float*)d_in[0];
    const int* labels  = (const int*)d_in[1];
    float* out = (float*)d_out;

    char* w = (char*)d_ws;
    float* countsf = (float*)(w + OFF_COUNTS);
    int* offs      = (int*)(w + OFF_OFFS);
    int* perm      = (int*)(w + OFF_PERM);
    float* negcnt  = (float*)(w + OFF_NEG);
    float* possum  = (float*)(w + OFF_POS);
    float* S       = (float*)(w + OFF_S);
    float* sq      = (float*)(w + OFF_SQ);
    float* dap     = (float*)(w + OFF_DAP);
    unsigned char* fb = (unsigned char*)(w + OFF_FB);
    u16* pd        = (u16*)(w + OFF_PD);

    // zero possum (at OFF_POS) and S (at OFF_S) in one memset
    hipMemsetAsync(w + OFF_POS, 0, (OFF_S - OFF_POS) + (size_t)B_ * P_ * 4, stream);

    k_counts<<<1, 256, 0, stream>>>(labels, countsf, offs, perm, negcnt);
    k_rowstats<<<B_, 256, 0, stream>>>(feats, fb, sq);
    k_pairs<<<dim3(8, 8, 8), 512, 0, stream>>>(fb, sq, labels, S, pd);
    k_dap<<<NID, 64, 0, stream>>>(S, sq, countsf, offs, perm, dap);
    k_lossred<<<B_, 256, 0, stream>>>(pd, dap, labels, possum);
    k_finalize<<<1, 1, 0, stream>>>(possum, negcnt, out);
}